// Round 3
// baseline (304.811 us; speedup 1.0000x reference)
//
#include <hip/hip_runtime.h>
#include <hip/hip_fp16.h>
#include <math.h>

#define NNODES 50000
#define NEDGES 800000
#define HD     128      // H*D
#define NHEADS 4
#define DH     32

#define TILE_R 64       // gemm rows per block
#define AKPF   136      // full-K padded stride (halves)

#define PTILE  128      // proj rows per block; split-K=2 partial buffers + reduce
                        // (round-6 lesson: NEVER split-K via global atomicAdd)

// Bucketed CSR build (round-9 lesson: naive 4B random scatter = 17x write amp;
// all fine-grained scatter must happen in LDS).
#define NBUCK  196
#define BCAP   6144
#define P1_T   512
#define P1_EPB 4096
#define P2_T   512

#define NDBIN  64       // degree bins for node permutation (round-19)

struct alignas(16) Half8 { __half2 a, b, c, d; };
typedef _Float16 f16x8 __attribute__((ext_vector_type(8)));
typedef float    f32x4 __attribute__((ext_vector_type(4)));
typedef float    f32x8 __attribute__((ext_vector_type(8)));

static __device__ __forceinline__ float lrelu(float x){ return x > 0.f ? x : 0.2f*x; }
static __device__ __forceinline__ float elu(float x){ return x > 0.f ? x : __expf(x) - 1.f; }

// ---------------- CSR build, bucketed ----------------

__global__ void init_btail_kernel(int* btail, int* gdhist){
  int b = blockIdx.x*blockDim.x + threadIdx.x;
  if (b < NBUCK) btail[b] = b*BCAP;
  if (b < NDBIN) gdhist[b] = 0;
}

__global__ __launch_bounds__(P1_T) void p1_bucket_kernel(
    const int* __restrict__ src, const int* __restrict__ dst,
    int* __restrict__ btail, unsigned int* __restrict__ bstage, int e)
{
  __shared__ int cnt[NBUCK];
  __shared__ int gstart[NBUCK];
  int t = threadIdx.x;
  int base = blockIdx.x * P1_EPB;
  for (int i = t; i < NBUCK; i += P1_T) cnt[i] = 0;
  __syncthreads();
  int s_[8], b_[8], dl_[8];
  #pragma unroll
  for (int j = 0; j < 8; j++){
    int i = base + j*P1_T + t;
    if (i < e){
      int d = dst[i];
      s_[j]  = src[i];
      b_[j]  = d >> 8;
      dl_[j] = d & 255;
      atomicAdd(&cnt[b_[j]], 1);
    } else b_[j] = -1;
  }
  __syncthreads();
  for (int i = t; i < NBUCK; i += P1_T){
    gstart[i] = cnt[i] ? atomicAdd(&btail[i], cnt[i]) : 0;
    cnt[i] = 0;
  }
  __syncthreads();
  #pragma unroll
  for (int j = 0; j < 8; j++){
    if (b_[j] >= 0){
      int p = atomicAdd(&cnt[b_[j]], 1);
      bstage[(size_t)gstart[b_[j]] + p] = ((unsigned)dl_[j] << 16) | (unsigned)s_[j];
    }
  }
}

// parallel bucket scan (round-19: old version was a serial 196-iter single thread)
__global__ __launch_bounds__(256) void bucket_scan_kernel(
    const int* __restrict__ btail, int* __restrict__ ebase, int* __restrict__ rowptr)
{
  __shared__ int c[256];
  int t = threadIdx.x;
  int mine = (t < NBUCK) ? (btail[t] - t*BCAP) : 0;
  c[t] = mine;
  __syncthreads();
  for (int off = 1; off < 256; off <<= 1){
    int v = 0;
    if (t >= off) v = c[t - off];
    __syncthreads();
    c[t] += v;
    __syncthreads();
  }
  if (t < NBUCK) ebase[t] = c[t] - mine;        // exclusive prefix
  if (t == NBUCK - 1) rowptr[NNODES] = c[t];
}

__global__ __launch_bounds__(P2_T) void p2_csr_kernel(
    const unsigned int* __restrict__ bstage, const int* __restrict__ btail,
    const int* __restrict__ ebase, int* __restrict__ rowptr, int* __restrict__ srcs,
    int* __restrict__ gdhist)
{
  __shared__ unsigned int ebuf[BCAP];
  __shared__ unsigned short sorted[BCAP];
  __shared__ int cnt[256], ofs[256], run[256];
  __shared__ int dh[NDBIN];
  int b = blockIdx.x, t = threadIdx.x;
  int nE = btail[b] - b*BCAP;
  int gb = ebase[b];
  const unsigned int* bp = bstage + (size_t)b*BCAP;

  for (int i = t; i < 256; i += P2_T) cnt[i] = 0;
  if (t < NDBIN) dh[t] = 0;
  __syncthreads();
  for (int i = t; i < nE; i += P2_T){
    unsigned int v = bp[i];
    ebuf[i] = v;
    atomicAdd(&cnt[v >> 16], 1);
  }
  __syncthreads();
  if (t < 256) ofs[t] = cnt[t];
  __syncthreads();
  for (int off = 1; off < 256; off <<= 1){
    int v = 0;
    if (t < 256 && t >= off) v = ofs[t - off];
    __syncthreads();
    if (t < 256) ofs[t] += v;
    __syncthreads();
  }
  if (t < 256){
    int ex = ofs[t] - cnt[t];
    run[t] = ex;
    int node = b*256 + t;
    if (node < NNODES){
      rowptr[node] = gb + ex;
      int dbin = cnt[t] > NDBIN-1 ? NDBIN-1 : cnt[t];   // degree histogram (round-19)
      atomicAdd(&dh[dbin], 1);
    }
  }
  __syncthreads();
  if (t < NDBIN && dh[t]) atomicAdd(&gdhist[t], dh[t]);
  for (int i = t; i < nE; i += P2_T){
    unsigned int v = ebuf[i];
    int p = atomicAdd(&run[v >> 16], 1);
    sorted[p] = (unsigned short)(v & 0xFFFFu);
  }
  __syncthreads();
  for (int i = t; i < nE; i += P2_T)
    srcs[gb + i] = (int)sorted[i];
}

// degree-bin prefix: run[bin] = exclusive base into perm[]
__global__ void dprefix_kernel(const int* __restrict__ gdhist, int* __restrict__ run){
  __shared__ int c[NDBIN];
  int t = threadIdx.x;            // 64 threads
  int mine = gdhist[t];
  c[t] = mine;
  __syncthreads();
  for (int off = 1; off < NDBIN; off <<= 1){
    int v = 0;
    if (t >= off) v = c[t - off];
    __syncthreads();
    c[t] += v;
    __syncthreads();
  }
  run[t] = c[t] - mine;
}

// scatter nodes into degree-sorted order (LDS-ranked, no hot global contention)
__global__ __launch_bounds__(256) void perm_scatter_kernel(
    const int* __restrict__ rowptr, int* __restrict__ run, int* __restrict__ perm)
{
  __shared__ int lh[NDBIN], bb[NDBIN];
  int t = threadIdx.x, node = blockIdx.x*256 + t;
  if (t < NDBIN) lh[t] = 0;
  __syncthreads();
  int dbin = -1;
  if (node < NNODES){
    int d = rowptr[node+1] - rowptr[node];
    dbin = d > NDBIN-1 ? NDBIN-1 : d;
    atomicAdd(&lh[dbin], 1);
  }
  __syncthreads();
  if (t < NDBIN){ bb[t] = lh[t] ? atomicAdd(&run[t], lh[t]) : 0; lh[t] = 0; }
  __syncthreads();
  if (dbin >= 0){
    int r = atomicAdd(&lh[dbin], 1);
    perm[bb[dbin] + r] = node;
  }
}

// ---------------- W prep: transpose+convert W[l][k][n] -> Wt[l][n][k] fp16 ----------------
__global__ void wprep_kernel(const float* __restrict__ W0, const float* __restrict__ W1,
                             const float* __restrict__ W2, _Float16* __restrict__ wt){
  int id = blockIdx.x*blockDim.x + threadIdx.x;     // 3*16384
  if (id >= 3*16384) return;
  int l = id >> 14, rem = id & 16383;
  int n = rem >> 7, k = rem & 127;
  const float* W = (l==0) ? W0 : (l==1) ? W1 : W2;
  wt[(size_t)l*16384 + n*128 + k] = (_Float16)W[k*128 + n];
}

// ---------------- GEMM (h @ W) via MFMA fp16, full-K single-barrier staging ----------------
// Templated input: layer 0 reads fp32 x (stride 128); layers 1-2 read fp16 emb
// (stride 384) directly — halves A-read traffic and drops the cvt (round-16).
template<bool FP16IN>
__global__ __launch_bounds__(256) void gemm_feat_kernel(
    const void* __restrict__ hin, int hstride,
    const _Float16* __restrict__ Wt,   // [128 n][128 k] fp16 (pre-transposed)
    const float* __restrict__ al, const float* __restrict__ ar,
    __half* __restrict__ feat, float* __restrict__ elv, float* __restrict__ erv)
{
  __shared__ __align__(16) _Float16 Ah[TILE_R*AKPF];  // 17408 B
  __shared__ __align__(16) _Float16 Wh[HD*AKPF];      // 34816 B
  int t = threadIdx.x;
  int w = t >> 6, lane = t & 63;
  int c = lane & 15, quad = lane >> 4;
  int rbase = blockIdx.x * TILE_R;

  f32x4 acc[8];
  #pragma unroll
  for (int ct = 0; ct < 8; ct++) acc[ct] = (f32x4){0.f, 0.f, 0.f, 0.f};

  int arow = t >> 2;
  int akq  = t & 3;
  int an   = rbase + arow;
  if (FP16IN){
    const _Float16* ap = (const _Float16*)hin + (size_t)an*hstride + akq*8;
    #pragma unroll
    for (int kb = 0; kb < HD; kb += 32){
      f16x8 av = (f16x8)((_Float16)0);
      if (an < NNODES) av = *(const f16x8*)(ap + kb);
      *(f16x8*)&Ah[arow*AKPF + kb + akq*8] = av;
    }
  } else {
    const float* ap = (const float*)hin + (size_t)an*hstride + akq*8;
    #pragma unroll
    for (int kb = 0; kb < HD; kb += 32){
      float4 v0 = make_float4(0.f,0.f,0.f,0.f), v1 = v0;
      if (an < NNODES){
        v0 = *(const float4*)(ap + kb);
        v1 = *(const float4*)(ap + kb + 4);
      }
      f16x8 av;
      av[0]=(_Float16)v0.x; av[1]=(_Float16)v0.y; av[2]=(_Float16)v0.z; av[3]=(_Float16)v0.w;
      av[4]=(_Float16)v1.x; av[5]=(_Float16)v1.y; av[6]=(_Float16)v1.z; av[7]=(_Float16)v1.w;
      *(f16x8*)&Ah[arow*AKPF + kb + akq*8] = av;
    }
  }
  int wn = t >> 1;
  int wk = (t & 1) * 16;
  const _Float16* wp = Wt + wn*HD + wk;
  #pragma unroll
  for (int kb = 0; kb < HD; kb += 32){
    *(uint4*)&Wh[wn*AKPF + kb + wk]     = *(const uint4*)(wp + kb);
    *(uint4*)&Wh[wn*AKPF + kb + wk + 8] = *(const uint4*)(wp + kb + 8);
  }
  __syncthreads();

  #pragma unroll
  for (int kb = 0; kb < HD; kb += 32){
    f16x8 afrag = *(const f16x8*)&Ah[(w*16 + c)*AKPF + kb + quad*8];
    #pragma unroll
    for (int ct = 0; ct < 8; ct++){
      f16x8 bfrag = *(const f16x8*)&Wh[(ct*16 + c)*AKPF + kb + quad*8];
      acc[ct] = __builtin_amdgcn_mfma_f32_16x16x32_f16(afrag, bfrag, acc[ct], 0, 0, 0);
    }
  }

  float alv[8], arv[8];
  #pragma unroll
  for (int ct = 0; ct < 8; ct++){
    int idx = (ct >> 1)*DH + (ct & 1)*16 + c;
    alv[ct] = al[idx];
    arv[ct] = ar[idx];
  }
  #pragma unroll
  for (int r = 0; r < 4; r++){
    int n = rbase + w*16 + quad*4 + r;
    float pl[4], pr[4];
    #pragma unroll
    for (int hh = 0; hh < 4; hh++){
      pl[hh] = acc[2*hh][r]*alv[2*hh] + acc[2*hh+1][r]*alv[2*hh+1];
      pr[hh] = acc[2*hh][r]*arv[2*hh] + acc[2*hh+1][r]*arv[2*hh+1];
    }
    #pragma unroll
    for (int hh = 0; hh < 4; hh++){
      pl[hh] += __shfl_xor(pl[hh], 1); pl[hh] += __shfl_xor(pl[hh], 2);
      pl[hh] += __shfl_xor(pl[hh], 4); pl[hh] += __shfl_xor(pl[hh], 8);
      pr[hh] += __shfl_xor(pr[hh], 1); pr[hh] += __shfl_xor(pr[hh], 2);
      pr[hh] += __shfl_xor(pr[hh], 4); pr[hh] += __shfl_xor(pr[hh], 8);
    }
    if (n < NNODES){
      if (c < 4){ elv[n*NHEADS + c] = pl[c]; erv[n*NHEADS + c] = pr[c]; }
      #pragma unroll
      for (int ct = 0; ct < 8; ct++)
        feat[(size_t)n*HD + ct*16 + c] = __float2half_rn(acc[ct][r]);
    }
  }
}

// -------- fused edge-softmax + aggregation: GROUP-OWNS-NODE + degree-sorted --------
// Round-17: 8-lane group owns one node (zero cross-lane reduce; ssum replicated).
// Round-18: 4+4 A/B software pipeline (32 edges in flight per wave).
// Round-19: wave trip count = MAX degree over its 8 co-resident nodes; with
// Poisson(16) degrees that's ~60% lane-slot efficiency (matched VALUBusy 58%).
// Process nodes in degree-binned order via perm[] so co-waved groups have
// near-identical degree -> max ~= avg. v_fma_mix fuses f16->f32 cvt into FMA.
// No max subtraction (round-9).
#define MIX2(alo, ahi, pk, aa) \
  asm("v_fma_mix_f32 %0, %2, %3, %0 op_sel:[0,0,0] op_sel_hi:[1,0,0]\n\t" \
      "v_fma_mix_f32 %1, %2, %3, %1 op_sel:[1,0,0] op_sel_hi:[1,0,0]" \
      : "+v"(alo), "+v"(ahi) : "v"(pk), "v"(aa))

__global__ __launch_bounds__(256) void smax_agg_kernel(
    const int* __restrict__ rowptr, const int* __restrict__ srcs,
    const int* __restrict__ perm,
    const float* __restrict__ elv, const float* __restrict__ erv,
    const __half* __restrict__ feat, __half* __restrict__ emb_out, int n)
{
  int g = (int)((blockIdx.x*(size_t)blockDim.x + threadIdx.x) >> 3);
  if (g >= n) return;
  int gid = perm[g];                  // degree-sorted node id
  int fl8  = threadIdx.x & 7;
  int fo   = fl8 * 16;          // this lane's 16-feature slice
  int head = fl8 >> 1;

  int s0 = rowptr[gid], s1 = rowptr[gid+1];
  float erh = erv[gid*4 + head];

  float acc[16];
  #pragma unroll
  for (int j = 0; j < 16; j++) acc[j] = 0.f;
  float ssum = 0.f;

  const uint4 zq = make_uint4(0,0,0,0);

  int   sA[4], sB[4];
  uint4 qA0[4], qA1[4], qB0[4], qB1[4];
  float eA[4], eB[4];

#define LOADB(base, S, Q0, Q1, EL)                                   \
  {                                                                  \
    _Pragma("unroll")                                                \
    for (int j = 0; j < 4; j++){                                     \
      int ee = (base) + j;                                           \
      S[j] = (ee < s1) ? srcs[ee] : -1;                              \
    }                                                                \
    _Pragma("unroll")                                                \
    for (int j = 0; j < 4; j++){                                     \
      if (S[j] >= 0){                                                \
        const __half* fr = feat + ((size_t)S[j] << 7) + fo;          \
        Q0[j] = *(const uint4*)(fr);                                 \
        Q1[j] = *(const uint4*)(fr + 8);                             \
        EL[j] = elv[S[j]*4 + head];                                  \
      } else { Q0[j] = zq; Q1[j] = zq; EL[j] = 0.f; }                \
    }                                                                \
  }

#define ACCB(S, Q0, Q1, EL)                                          \
  {                                                                  \
    _Pragma("unroll")                                                \
    for (int j = 0; j < 4; j++){                                     \
      float x = EL[j] + erh;                                         \
      float a = (S[j] >= 0) ? __expf(fmaxf(x, 0.2f*x)) : 0.f;        \
      ssum += a;                                                     \
      MIX2(acc[0],  acc[1],  Q0[j].x, a);                            \
      MIX2(acc[2],  acc[3],  Q0[j].y, a);                            \
      MIX2(acc[4],  acc[5],  Q0[j].z, a);                            \
      MIX2(acc[6],  acc[7],  Q0[j].w, a);                            \
      MIX2(acc[8],  acc[9],  Q1[j].x, a);                            \
      MIX2(acc[10], acc[11], Q1[j].y, a);                            \
      MIX2(acc[12], acc[13], Q1[j].z, a);                            \
      MIX2(acc[14], acc[15], Q1[j].w, a);                            \
    }                                                                \
  }

  LOADB(s0, sA, qA0, qA1, eA);
  for (int e = s0; e < s1; e += 8){
    LOADB(e + 4, sB, qB0, qB1, eB);
    ACCB(sA, qA0, qA1, eA);
    LOADB(e + 8, sA, qA0, qA1, eA);
    ACCB(sB, qB0, qB1, eB);
  }
#undef LOADB
#undef ACCB

  // ssum is identical across the group's 8 lanes: no reduction needed.
  // deg-0 node: ssum=0 -> inv=0 -> elu(0)=0 (matches reference zeros).
  float inv = (ssum > 0.f) ? 1.f / ssum : 0.f;
  __half2 hv[8];
  #pragma unroll
  for (int j = 0; j < 8; j++)
    hv[j] = __floats2half2_rn(elu(acc[2*j]*inv), elu(acc[2*j+1]*inv));
  __half* op = emb_out + (size_t)gid*384 + fo;
  *(uint4*)(op)     = *(uint4*)&hv[0];
  *(uint4*)(op + 8) = *(uint4*)&hv[4];
}

// ---------------- final projection: emb[N,384] fp16 @ Wproj[384,32], split-K partials ----
__global__ __launch_bounds__(256) void proj_kernel(
    const __half* __restrict__ emb, const float* __restrict__ Wp, float* __restrict__ part)
{
  __shared__ float As[PTILE*36];
  __shared__ float Wl[32*32];
  int t = threadIdx.x;
  int tx = t & 3, ty = t >> 2;
  int rbase = blockIdx.x * PTILE;
  int kstart = blockIdx.y * 192;
  float* pout = part + (size_t)blockIdx.y * NNODES * 32;

  float acc[2][8];
  #pragma unroll
  for (int r = 0; r < 2; r++)
    #pragma unroll
    for (int j = 0; j < 8; j++) acc[r][j] = 0.f;

  for (int kb = kstart; kb < kstart + 192; kb += 32){
    // stage A: 128 rows x 32 k = 4096 halves = 512 h8-chunks, 2 per thread
    #pragma unroll
    for (int i = 0; i < 2; i++){
      int idx = i*256 + t;          // 0..511
      int row = idx >> 2;           // 0..127
      int kq  = (idx & 3) * 8;      // 0,8,16,24
      int gr  = rbase + row;
      f16x8 v = (f16x8)((_Float16)0);
      if (gr < NNODES) v = *(const f16x8*)((const _Float16*)emb + (size_t)gr*384 + kb + kq);
      float4 f0, f1;
      f0.x=(float)v[0]; f0.y=(float)v[1]; f0.z=(float)v[2]; f0.w=(float)v[3];
      f1.x=(float)v[4]; f1.y=(float)v[5]; f1.z=(float)v[6]; f1.w=(float)v[7];
      *(float4*)&As[row*36 + kq]     = f0;
      *(float4*)&As[row*36 + kq + 4] = f1;
    }
    *(float4*)&Wl[t*4] = *(const float4*)(Wp + (size_t)kb*32 + t*4);
    __syncthreads();

    #pragma unroll 8
    for (int k = 0; k < 32; k++){
      float4 b0 = *(const float4*)&Wl[k*32 + tx*8];
      float4 b1 = *(const float4*)&Wl[k*32 + tx*8 + 4];
      #pragma unroll
      for (int r = 0; r < 2; r++){
        float a = As[(ty + 64*r)*36 + k];
        acc[r][0] += a*b0.x; acc[r][1] += a*b0.y;
        acc[r][2] += a*b0.z; acc[r][3] += a*b0.w;
        acc[r][4] += a*b1.x; acc[r][5] += a*b1.y;
        acc[r][6] += a*b1.z; acc[r][7] += a*b1.w;
      }
    }
    __syncthreads();
  }

  #pragma unroll
  for (int r = 0; r < 2; r++){
    int n = rbase + ty + 64*r;
    if (n < NNODES){
      *(float4*)(pout + (size_t)n*32 + tx*8)     = make_float4(acc[r][0], acc[r][1], acc[r][2], acc[r][3]);
      *(float4*)(pout + (size_t)n*32 + tx*8 + 4) = make_float4(acc[r][4], acc[r][5], acc[r][6], acc[r][7]);
    }
  }
}

__global__ void proj_reduce_kernel(const float4* __restrict__ part, float4* __restrict__ out, int n4){
  int i = blockIdx.x*blockDim.x + threadIdx.x;
  if (i >= n4) return;
  float4 a = part[i];
  float4 b = part[n4 + i];
  out[i] = make_float4(a.x + b.x, a.y + b.y, a.z + b.z, a.w + b.w);
}

// ---------------- launch ----------------
extern "C" void kernel_launch(void* const* d_in, const int* in_sizes, int n_in,
                              void* d_out, int out_size, void* d_ws, size_t ws_size,
                              hipStream_t stream) {
  const float* x    = (const float*)d_in[0];
  const int*   src  = (const int*)d_in[1];
  const int*   dst  = (const int*)d_in[2];
  const float* Ws_[3]  = { (const float*)d_in[3], (const float*)d_in[6], (const float*)d_in[9]  };
  const float* als[3] = { (const float*)d_in[4], (const float*)d_in[7], (const float*)d_in[10] };
  const float* ars[3] = { (const float*)d_in[5], (const float*)d_in[8], (const float*)d_in[11] };
  const float* Wproj  = (const float*)d_in[12];
  float* out = (float*)d_out;

  char* wptr = (char*)d_ws;
  auto alloc = [&](size_t bytes) -> void* {
    void* p = (void*)wptr; wptr += (bytes + 255) & ~(size_t)255; return p;
  };
  int*      btail      = (int*)     alloc((size_t)NBUCK*4);
  int*      ebase      = (int*)     alloc((size_t)NBUCK*4);
  unsigned* bstage     = (unsigned*)alloc((size_t)NBUCK*BCAP*4);
  int*      rowptr     = (int*)     alloc((size_t)(NNODES+1)*4);
  int*      src_sorted = (int*)     alloc((size_t)NEDGES*4);
  __half*   feat       = (__half*)  alloc((size_t)NNODES*HD*2);
  float*    elv        = (float*)   alloc((size_t)NNODES*NHEADS*4);
  float*    erv        = (float*)   alloc((size_t)NNODES*NHEADS*4);
  __half*   emb        = (__half*)  alloc((size_t)NNODES*384*2);
  float*    part       = (float*)   alloc((size_t)2*NNODES*32*4);
  _Float16* wt         = (_Float16*)alloc((size_t)3*HD*HD*2);
  int*      gdhist     = (int*)     alloc((size_t)NDBIN*4);
  int*      drun       = (int*)     alloc((size_t)NDBIN*4);
  int*      perm       = (int*)     alloc((size_t)NNODES*4);

  // CSR build, bucketed (LDS-local scatter) + degree-binned node permutation
  init_btail_kernel<<<1, 256, 0, stream>>>(btail, gdhist);
  p1_bucket_kernel<<<(NEDGES + P1_EPB - 1)/P1_EPB, P1_T, 0, stream>>>(
      src, dst, btail, bstage, NEDGES);
  bucket_scan_kernel<<<1, 256, 0, stream>>>(btail, ebase, rowptr);
  p2_csr_kernel<<<NBUCK, P2_T, 0, stream>>>(bstage, btail, ebase, rowptr, src_sorted, gdhist);
  dprefix_kernel<<<1, NDBIN, 0, stream>>>(gdhist, drun);
  perm_scatter_kernel<<<NBUCK, 256, 0, stream>>>(rowptr, drun, perm);

  // W transpose+fp16 prep (all 3 layers)
  wprep_kernel<<<(3*HD*HD + 255)/256, 256, 0, stream>>>(Ws_[0], Ws_[1], Ws_[2], wt);

  const int NGB = (NNODES + TILE_R - 1)/TILE_R;
  const int NSMB = (NNODES*8 + 255)/256;     // 8 lanes per node
  // layer 0: fp32 x input
  gemm_feat_kernel<false><<<NGB, 256, 0, stream>>>(
      (const void*)x, 128, wt, als[0], ars[0], feat, elv, erv);
  smax_agg_kernel<<<NSMB, 256, 0, stream>>>(rowptr, src_sorted, perm, elv, erv,
                                            feat, emb, NNODES);
  // layers 1,2: fp16 emb input (previous layer's 128-wide slice)
  for (int l = 1; l < 3; l++){
    gemm_feat_kernel<true><<<NGB, 256, 0, stream>>>(
        (const void*)(emb + (size_t)(l-1)*128), 384,
        wt + (size_t)l*HD*HD, als[l], ars[l], feat, elv, erv);
    smax_agg_kernel<<<NSMB, 256, 0, stream>>>(rowptr, src_sorted, perm, elv, erv,
                                              feat, emb + (size_t)l*128, NNODES);
  }

  dim3 pgrid((NNODES + PTILE - 1)/PTILE, 2);
  proj_kernel<<<pgrid, 256, 0, stream>>>(emb, Wproj, part);
  const int OUT4 = NNODES*32/4;
  proj_reduce_kernel<<<(OUT4+255)/256, 256, 0, stream>>>((const float4*)part, (float4*)out, OUT4);
}

// Round 4
// 273.061 us; speedup vs baseline: 1.1163x; 1.1163x over previous
//
#include <hip/hip_runtime.h>
#include <hip/hip_fp16.h>
#include <math.h>

#define NNODES 50000
#define NEDGES 800000
#define HD     128      // H*D
#define NHEADS 4
#define DH     32

#define TILE_R 64       // gemm rows per block
#define AKPF   136      // full-K padded stride (halves)

// Bucketed CSR build (round-9 lesson: naive 4B random scatter = 17x write amp;
// all fine-grained scatter must happen in LDS).
#define NBUCK  196
#define BCAP   6144
#define P1_T   512
#define P1_EPB 4096
#define P2_T   512

struct alignas(16) Half8 { __half2 a, b, c, d; };
typedef _Float16 f16x8 __attribute__((ext_vector_type(8)));
typedef float    f32x4 __attribute__((ext_vector_type(4)));
typedef float    f32x8 __attribute__((ext_vector_type(8)));

static __device__ __forceinline__ float lrelu(float x){ return x > 0.f ? x : 0.2f*x; }
static __device__ __forceinline__ float elu(float x){ return x > 0.f ? x : __expf(x) - 1.f; }

// ---------------- fused prep: btail init + W transpose/cvt + Wproj transpose/cvt ----
// (round-20: merged 2 tiny kernels + new Wproj prep into one launch)
__global__ void prep_kernel(const float* __restrict__ W0, const float* __restrict__ W1,
                            const float* __restrict__ W2, const float* __restrict__ Wp,
                            _Float16* __restrict__ wt, _Float16* __restrict__ wt2,
                            int* __restrict__ btail){
  int id = blockIdx.x*blockDim.x + threadIdx.x;
  if (id < NBUCK) btail[id] = id*BCAP;
  if (id < 3*16384){
    int l = id >> 14, rem = id & 16383;
    int n = rem >> 7, k = rem & 127;
    const float* W = (l==0) ? W0 : (l==1) ? W1 : W2;
    wt[(size_t)l*16384 + n*128 + k] = (_Float16)W[k*128 + n];
  } else if (id < 3*16384 + 12288){
    int rem = id - 3*16384;
    int k = rem >> 5, n = rem & 31;      // Wproj[384][32] -> wt2[32][384]
    wt2[n*384 + k] = (_Float16)Wp[k*32 + n];
  }
}

// ---------------- CSR build, bucketed ----------------

__global__ __launch_bounds__(P1_T) void p1_bucket_kernel(
    const int* __restrict__ src, const int* __restrict__ dst,
    int* __restrict__ btail, unsigned int* __restrict__ bstage, int e)
{
  __shared__ int cnt[NBUCK];
  __shared__ int gstart[NBUCK];
  int t = threadIdx.x;
  int base = blockIdx.x * P1_EPB;
  for (int i = t; i < NBUCK; i += P1_T) cnt[i] = 0;
  __syncthreads();
  int s_[8], b_[8], dl_[8];
  #pragma unroll
  for (int j = 0; j < 8; j++){
    int i = base + j*P1_T + t;
    if (i < e){
      int d = dst[i];
      s_[j]  = src[i];
      b_[j]  = d >> 8;
      dl_[j] = d & 255;
      atomicAdd(&cnt[b_[j]], 1);
    } else b_[j] = -1;
  }
  __syncthreads();
  for (int i = t; i < NBUCK; i += P1_T){
    gstart[i] = cnt[i] ? atomicAdd(&btail[i], cnt[i]) : 0;
    cnt[i] = 0;
  }
  __syncthreads();
  #pragma unroll
  for (int j = 0; j < 8; j++){
    if (b_[j] >= 0){
      int p = atomicAdd(&cnt[b_[j]], 1);
      bstage[(size_t)gstart[b_[j]] + p] = ((unsigned)dl_[j] << 16) | (unsigned)s_[j];
    }
  }
}

// parallel bucket scan (round-19: old version was a serial 196-iter single thread)
__global__ __launch_bounds__(256) void bucket_scan_kernel(
    const int* __restrict__ btail, int* __restrict__ ebase, int* __restrict__ rowptr)
{
  __shared__ int c[256];
  int t = threadIdx.x;
  int mine = (t < NBUCK) ? (btail[t] - t*BCAP) : 0;
  c[t] = mine;
  __syncthreads();
  for (int off = 1; off < 256; off <<= 1){
    int v = 0;
    if (t >= off) v = c[t - off];
    __syncthreads();
    c[t] += v;
    __syncthreads();
  }
  if (t < NBUCK) ebase[t] = c[t] - mine;        // exclusive prefix
  if (t == NBUCK - 1) rowptr[NNODES] = c[t];
}

__global__ __launch_bounds__(P2_T) void p2_csr_kernel(
    const unsigned int* __restrict__ bstage, const int* __restrict__ btail,
    const int* __restrict__ ebase, int* __restrict__ rowptr, int* __restrict__ srcs)
{
  __shared__ unsigned int ebuf[BCAP];
  __shared__ unsigned short sorted[BCAP];
  __shared__ int cnt[256], ofs[256], run[256];
  int b = blockIdx.x, t = threadIdx.x;
  int nE = btail[b] - b*BCAP;
  int gb = ebase[b];
  const unsigned int* bp = bstage + (size_t)b*BCAP;

  for (int i = t; i < 256; i += P2_T) cnt[i] = 0;
  __syncthreads();
  for (int i = t; i < nE; i += P2_T){
    unsigned int v = bp[i];
    ebuf[i] = v;
    atomicAdd(&cnt[v >> 16], 1);
  }
  __syncthreads();
  if (t < 256) ofs[t] = cnt[t];
  __syncthreads();
  for (int off = 1; off < 256; off <<= 1){
    int v = 0;
    if (t < 256 && t >= off) v = ofs[t - off];
    __syncthreads();
    if (t < 256) ofs[t] += v;
    __syncthreads();
  }
  if (t < 256){
    int ex = ofs[t] - cnt[t];
    run[t] = ex;
    int node = b*256 + t;
    if (node < NNODES) rowptr[node] = gb + ex;
  }
  __syncthreads();
  for (int i = t; i < nE; i += P2_T){
    unsigned int v = ebuf[i];
    int p = atomicAdd(&run[v >> 16], 1);
    sorted[p] = (unsigned short)(v & 0xFFFFu);
  }
  __syncthreads();
  for (int i = t; i < nE; i += P2_T)
    srcs[gb + i] = (int)sorted[i];
}

// ---------------- GEMM (h @ W) via MFMA fp16, full-K single-barrier staging ----------------
// Templated input: layer 0 reads fp32 x (stride 128); layers 1-2 read fp16 emb
// (stride 384) directly — halves A-read traffic and drops the cvt (round-16).
template<bool FP16IN>
__global__ __launch_bounds__(256) void gemm_feat_kernel(
    const void* __restrict__ hin, int hstride,
    const _Float16* __restrict__ Wt,   // [128 n][128 k] fp16 (pre-transposed)
    const float* __restrict__ al, const float* __restrict__ ar,
    __half* __restrict__ feat, float* __restrict__ elv, float* __restrict__ erv)
{
  __shared__ __align__(16) _Float16 Ah[TILE_R*AKPF];  // 17408 B
  __shared__ __align__(16) _Float16 Wh[HD*AKPF];      // 34816 B
  int t = threadIdx.x;
  int w = t >> 6, lane = t & 63;
  int c = lane & 15, quad = lane >> 4;
  int rbase = blockIdx.x * TILE_R;

  f32x4 acc[8];
  #pragma unroll
  for (int ct = 0; ct < 8; ct++) acc[ct] = (f32x4){0.f, 0.f, 0.f, 0.f};

  int arow = t >> 2;
  int akq  = t & 3;
  int an   = rbase + arow;
  if (FP16IN){
    const _Float16* ap = (const _Float16*)hin + (size_t)an*hstride + akq*8;
    #pragma unroll
    for (int kb = 0; kb < HD; kb += 32){
      f16x8 av = (f16x8)((_Float16)0);
      if (an < NNODES) av = *(const f16x8*)(ap + kb);
      *(f16x8*)&Ah[arow*AKPF + kb + akq*8] = av;
    }
  } else {
    const float* ap = (const float*)hin + (size_t)an*hstride + akq*8;
    #pragma unroll
    for (int kb = 0; kb < HD; kb += 32){
      float4 v0 = make_float4(0.f,0.f,0.f,0.f), v1 = v0;
      if (an < NNODES){
        v0 = *(const float4*)(ap + kb);
        v1 = *(const float4*)(ap + kb + 4);
      }
      f16x8 av;
      av[0]=(_Float16)v0.x; av[1]=(_Float16)v0.y; av[2]=(_Float16)v0.z; av[3]=(_Float16)v0.w;
      av[4]=(_Float16)v1.x; av[5]=(_Float16)v1.y; av[6]=(_Float16)v1.z; av[7]=(_Float16)v1.w;
      *(f16x8*)&Ah[arow*AKPF + kb + akq*8] = av;
    }
  }
  int wn = t >> 1;
  int wk = (t & 1) * 16;
  const _Float16* wp = Wt + wn*HD + wk;
  #pragma unroll
  for (int kb = 0; kb < HD; kb += 32){
    *(uint4*)&Wh[wn*AKPF + kb + wk]     = *(const uint4*)(wp + kb);
    *(uint4*)&Wh[wn*AKPF + kb + wk + 8] = *(const uint4*)(wp + kb + 8);
  }
  __syncthreads();

  #pragma unroll
  for (int kb = 0; kb < HD; kb += 32){
    f16x8 afrag = *(const f16x8*)&Ah[(w*16 + c)*AKPF + kb + quad*8];
    #pragma unroll
    for (int ct = 0; ct < 8; ct++){
      f16x8 bfrag = *(const f16x8*)&Wh[(ct*16 + c)*AKPF + kb + quad*8];
      acc[ct] = __builtin_amdgcn_mfma_f32_16x16x32_f16(afrag, bfrag, acc[ct], 0, 0, 0);
    }
  }

  float alv[8], arv[8];
  #pragma unroll
  for (int ct = 0; ct < 8; ct++){
    int idx = (ct >> 1)*DH + (ct & 1)*16 + c;
    alv[ct] = al[idx];
    arv[ct] = ar[idx];
  }
  #pragma unroll
  for (int r = 0; r < 4; r++){
    int n = rbase + w*16 + quad*4 + r;
    float pl[4], pr[4];
    #pragma unroll
    for (int hh = 0; hh < 4; hh++){
      pl[hh] = acc[2*hh][r]*alv[2*hh] + acc[2*hh+1][r]*alv[2*hh+1];
      pr[hh] = acc[2*hh][r]*arv[2*hh] + acc[2*hh+1][r]*arv[2*hh+1];
    }
    #pragma unroll
    for (int hh = 0; hh < 4; hh++){
      pl[hh] += __shfl_xor(pl[hh], 1); pl[hh] += __shfl_xor(pl[hh], 2);
      pl[hh] += __shfl_xor(pl[hh], 4); pl[hh] += __shfl_xor(pl[hh], 8);
      pr[hh] += __shfl_xor(pr[hh], 1); pr[hh] += __shfl_xor(pr[hh], 2);
      pr[hh] += __shfl_xor(pr[hh], 4); pr[hh] += __shfl_xor(pr[hh], 8);
    }
    if (n < NNODES){
      if (c < 4){ elv[n*NHEADS + c] = pl[c]; erv[n*NHEADS + c] = pr[c]; }
      #pragma unroll
      for (int ct = 0; ct < 8; ct++)
        feat[(size_t)n*HD + ct*16 + c] = __float2half_rn(acc[ct][r]);
    }
  }
}

// -------- fused edge-softmax + aggregation: GROUP-OWNS-NODE + 4-deep pipeline --------
// Round-17: 8-lane group owns one node (zero cross-lane reduce; ssum replicated).
// Round-18: 4+4 A/B software pipeline (32 edges in flight per wave).
// Round-19 lesson: degree-sorting was NEUTRAL (+5us prep cost) — the kernel is
// bound by the random feat gather (89MB L2-miss @ ~2.4TB/s, near the random-256B
// floor: feat 12.8MB >> 4MB per-XCD L2, random graph = no locality to mine).
// v_fma_mix fuses f16->f32 cvt into FMA. No max subtraction (round-9).
#define MIX2(alo, ahi, pk, aa) \
  asm("v_fma_mix_f32 %0, %2, %3, %0 op_sel:[0,0,0] op_sel_hi:[1,0,0]\n\t" \
      "v_fma_mix_f32 %1, %2, %3, %1 op_sel:[1,0,0] op_sel_hi:[1,0,0]" \
      : "+v"(alo), "+v"(ahi) : "v"(pk), "v"(aa))

__global__ __launch_bounds__(256) void smax_agg_kernel(
    const int* __restrict__ rowptr, const int* __restrict__ srcs,
    const float* __restrict__ elv, const float* __restrict__ erv,
    const __half* __restrict__ feat, __half* __restrict__ emb_out, int n)
{
  int gid = (int)((blockIdx.x*(size_t)blockDim.x + threadIdx.x) >> 3);  // node
  if (gid >= n) return;
  int fl8  = threadIdx.x & 7;
  int fo   = fl8 * 16;          // this lane's 16-feature slice
  int head = fl8 >> 1;

  int s0 = rowptr[gid], s1 = rowptr[gid+1];
  float erh = erv[gid*4 + head];

  float acc[16];
  #pragma unroll
  for (int j = 0; j < 16; j++) acc[j] = 0.f;
  float ssum = 0.f;

  const uint4 zq = make_uint4(0,0,0,0);

  int   sA[4], sB[4];
  uint4 qA0[4], qA1[4], qB0[4], qB1[4];
  float eA[4], eB[4];

#define LOADB(base, S, Q0, Q1, EL)                                   \
  {                                                                  \
    _Pragma("unroll")                                                \
    for (int j = 0; j < 4; j++){                                     \
      int ee = (base) + j;                                           \
      S[j] = (ee < s1) ? srcs[ee] : -1;                              \
    }                                                                \
    _Pragma("unroll")                                                \
    for (int j = 0; j < 4; j++){                                     \
      if (S[j] >= 0){                                                \
        const __half* fr = feat + ((size_t)S[j] << 7) + fo;          \
        Q0[j] = *(const uint4*)(fr);                                 \
        Q1[j] = *(const uint4*)(fr + 8);                             \
        EL[j] = elv[S[j]*4 + head];                                  \
      } else { Q0[j] = zq; Q1[j] = zq; EL[j] = 0.f; }                \
    }                                                                \
  }

#define ACCB(S, Q0, Q1, EL)                                          \
  {                                                                  \
    _Pragma("unroll")                                                \
    for (int j = 0; j < 4; j++){                                     \
      float x = EL[j] + erh;                                         \
      float a = (S[j] >= 0) ? __expf(fmaxf(x, 0.2f*x)) : 0.f;        \
      ssum += a;                                                     \
      MIX2(acc[0],  acc[1],  Q0[j].x, a);                            \
      MIX2(acc[2],  acc[3],  Q0[j].y, a);                            \
      MIX2(acc[4],  acc[5],  Q0[j].z, a);                            \
      MIX2(acc[6],  acc[7],  Q0[j].w, a);                            \
      MIX2(acc[8],  acc[9],  Q1[j].x, a);                            \
      MIX2(acc[10], acc[11], Q1[j].y, a);                            \
      MIX2(acc[12], acc[13], Q1[j].z, a);                            \
      MIX2(acc[14], acc[15], Q1[j].w, a);                            \
    }                                                                \
  }

  LOADB(s0, sA, qA0, qA1, eA);
  for (int e = s0; e < s1; e += 8){
    LOADB(e + 4, sB, qB0, qB1, eB);
    ACCB(sA, qA0, qA1, eA);
    LOADB(e + 8, sA, qA0, qA1, eA);
    ACCB(sB, qB0, qB1, eB);
  }
#undef LOADB
#undef ACCB

  // ssum is identical across the group's 8 lanes: no reduction needed.
  // deg-0 node: ssum=0 -> inv=0 -> elu(0)=0 (matches reference zeros).
  float inv = (ssum > 0.f) ? 1.f / ssum : 0.f;
  __half2 hv[8];
  #pragma unroll
  for (int j = 0; j < 8; j++)
    hv[j] = __floats2half2_rn(elu(acc[2*j]*inv), elu(acc[2*j+1]*inv));
  __half* op = emb_out + (size_t)gid*384 + fo;
  *(uint4*)(op)     = *(uint4*)&hv[0];
  *(uint4*)(op + 8) = *(uint4*)&hv[4];
}

// ---------------- final projection via MFMA: emb[N,384] fp16 @ Wproj[384,32] ----------------
// Round-20: replaces split-K fp32 VALU proj + reduce (57MB traffic) with a
// single MFMA kernel, K=384 in-block (3 k-chunks of 128). Wproj pre-transposed
// to fp16 [32][384] by prep_kernel. Output written directly (6.4MB).
__global__ __launch_bounds__(256) void proj_mfma_kernel(
    const __half* __restrict__ emb, const _Float16* __restrict__ Wt2,
    float* __restrict__ out)
{
  __shared__ __align__(16) _Float16 Ah[128*136];   // 34816 B (k-chunk of 128)
  __shared__ __align__(16) _Float16 Bh[32*392];    // 25088 B (full B)
  int t = threadIdx.x;
  int w = t >> 6, lane = t & 63;
  int c = lane & 15, quad = lane >> 4;
  int rbase = blockIdx.x * 128;

  f32x4 acc[2][2];
  #pragma unroll
  for (int rt = 0; rt < 2; rt++)
    #pragma unroll
    for (int ct = 0; ct < 2; ct++) acc[rt][ct] = (f32x4){0.f,0.f,0.f,0.f};

  // stage B once: 32 rows x 384 halves = 1536 h8-chunks, 6 per thread
  #pragma unroll
  for (int i = 0; i < 6; i++){
    int idx = i*256 + t;
    int row = idx / 48;
    int q8  = idx - row*48;
    *(f16x8*)&Bh[row*392 + q8*8] = *(const f16x8*)(Wt2 + row*384 + q8*8);
  }

  for (int kc = 0; kc < 384; kc += 128){
    // stage A chunk: 128 rows x 128 halves = 2048 h8-chunks, 8 per thread
    #pragma unroll
    for (int i = 0; i < 8; i++){
      int idx = i*256 + t;
      int row = idx >> 4;
      int q   = idx & 15;
      int gr  = rbase + row;
      f16x8 v = (f16x8)((_Float16)0);
      if (gr < NNODES) v = *(const f16x8*)((const _Float16*)emb + (size_t)gr*384 + kc + q*8);
      *(f16x8*)&Ah[row*136 + q*8] = v;
    }
    __syncthreads();
    #pragma unroll
    for (int kb = 0; kb < 128; kb += 32){
      #pragma unroll
      for (int rt = 0; rt < 2; rt++){
        f16x8 afrag = *(const f16x8*)&Ah[(w*32 + rt*16 + c)*136 + kb + quad*8];
        #pragma unroll
        for (int ct = 0; ct < 2; ct++){
          f16x8 bfrag = *(const f16x8*)&Bh[(ct*16 + c)*392 + kc + kb + quad*8];
          acc[rt][ct] = __builtin_amdgcn_mfma_f32_16x16x32_f16(afrag, bfrag, acc[rt][ct], 0, 0, 0);
        }
      }
    }
    __syncthreads();
  }

  #pragma unroll
  for (int rt = 0; rt < 2; rt++)
    #pragma unroll
    for (int r = 0; r < 4; r++){
      int n = rbase + w*32 + rt*16 + quad*4 + r;
      if (n < NNODES){
        out[(size_t)n*32 + c]      = acc[rt][0][r];
        out[(size_t)n*32 + 16 + c] = acc[rt][1][r];
      }
    }
}

// ---------------- launch ----------------
extern "C" void kernel_launch(void* const* d_in, const int* in_sizes, int n_in,
                              void* d_out, int out_size, void* d_ws, size_t ws_size,
                              hipStream_t stream) {
  const float* x    = (const float*)d_in[0];
  const int*   src  = (const int*)d_in[1];
  const int*   dst  = (const int*)d_in[2];
  const float* Ws_[3]  = { (const float*)d_in[3], (const float*)d_in[6], (const float*)d_in[9]  };
  const float* als[3] = { (const float*)d_in[4], (const float*)d_in[7], (const float*)d_in[10] };
  const float* ars[3] = { (const float*)d_in[5], (const float*)d_in[8], (const float*)d_in[11] };
  const float* Wproj  = (const float*)d_in[12];
  float* out = (float*)d_out;

  char* wptr = (char*)d_ws;
  auto alloc = [&](size_t bytes) -> void* {
    void* p = (void*)wptr; wptr += (bytes + 255) & ~(size_t)255; return p;
  };
  int*      btail      = (int*)     alloc((size_t)NBUCK*4);
  int*      ebase      = (int*)     alloc((size_t)NBUCK*4);
  unsigned* bstage     = (unsigned*)alloc((size_t)NBUCK*BCAP*4);
  int*      rowptr     = (int*)     alloc((size_t)(NNODES+1)*4);
  int*      src_sorted = (int*)     alloc((size_t)NEDGES*4);
  __half*   feat       = (__half*)  alloc((size_t)NNODES*HD*2);
  float*    elv        = (float*)   alloc((size_t)NNODES*NHEADS*4);
  float*    erv        = (float*)   alloc((size_t)NNODES*NHEADS*4);
  __half*   emb        = (__half*)  alloc((size_t)NNODES*384*2);
  _Float16* wt         = (_Float16*)alloc((size_t)3*HD*HD*2);
  _Float16* wt2        = (_Float16*)alloc((size_t)32*384*2);

  // fused prep: btail init + W/Wproj transpose+fp16 (1 launch, round-20)
  prep_kernel<<<(3*16384 + 12288 + 255)/256, 256, 0, stream>>>(
      Ws_[0], Ws_[1], Ws_[2], Wproj, wt, wt2, btail);

  // CSR build, bucketed (LDS-local scatter)
  p1_bucket_kernel<<<(NEDGES + P1_EPB - 1)/P1_EPB, P1_T, 0, stream>>>(
      src, dst, btail, bstage, NEDGES);
  bucket_scan_kernel<<<1, 256, 0, stream>>>(btail, ebase, rowptr);
  p2_csr_kernel<<<NBUCK, P2_T, 0, stream>>>(bstage, btail, ebase, rowptr, src_sorted);

  const int NGB = (NNODES + TILE_R - 1)/TILE_R;
  const int NSMB = (NNODES*8 + 255)/256;     // 8 lanes per node
  // layer 0: fp32 x input
  gemm_feat_kernel<false><<<NGB, 256, 0, stream>>>(
      (const void*)x, 128, wt, als[0], ars[0], feat, elv, erv);
  smax_agg_kernel<<<NSMB, 256, 0, stream>>>(rowptr, src_sorted, elv, erv,
                                            feat, emb, NNODES);
  // layers 1,2: fp16 emb input (previous layer's 128-wide slice)
  for (int l = 1; l < 3; l++){
    gemm_feat_kernel<true><<<NGB, 256, 0, stream>>>(
        (const void*)(emb + (size_t)(l-1)*128), 384,
        wt + (size_t)l*HD*HD, als[l], ars[l], feat, elv, erv);
    smax_agg_kernel<<<NSMB, 256, 0, stream>>>(rowptr, src_sorted, elv, erv,
                                              feat, emb + (size_t)l*128, NNODES);
  }

  // final projection (MFMA, no split-K, direct write)
  proj_mfma_kernel<<<(NNODES + 127)/128, 256, 0, stream>>>(emb, wt2, out);
}